// Round 3
// baseline (818.372 us; speedup 1.0000x reference)
//
#include <hip/hip_runtime.h>

// BGNN-A fused kernel for MI355X (gfx950), MFMA version.
// Inputs (fp32): x[12288,64], edge_index[12288,12288] (binary 0/1), weight[64,32], bias[32]
// out (fp32): [12288, 32]
//
// Math (binary off-diagonal adjacency => E^2 == E off-diagonal):
//   xw = x @ w                                  [N,32] fp32
//   B channels (128): [hi(xw) | hi(xw^2) | lo(xw) | lo(xw^2)]   (bf16 hi/lo split)
//   C = E_bf16 @ B   (MFMA, fp32 accum); S[.,c] = C[.,c] + C[.,c+64], c in 0..63
//   rowsum_e[i] = sum_j E[i,j]  (integer-exact, VALU side-accumulate)
//   diag fixups (adj = E + I, d = e_ii + 1):
//     s[c]  = S[i,c]    + xw[i,c]
//     t[c]  = S[i,32+c] + (e_ii ? 3 : 1) * xw2[i,c]      // (e_ii+1)^2 - e_ii
//     rs    = rowsum_e + 1 ; sumsq = rowsum_e - e_ii + d^2   (all exact ints in fp32)
//   denom = rs^2 - sumsq ; norm = denom==0 ? 0 : 1/denom  (ref: inf -> 0)
//   out[i,c] = norm * (s^2 - t) + bias[c]
//
// rsa*rsa needs 26 bits (rowsum ~ 6145) -> rounds, but identically to the
// reference's jnp.square(row_sum): same exact fp32 input, same IEEE-RN multiply.

#define NN 12288
#define IN_CH 64
#define OUT_CH 32
#define KC 8               // K chunks
#define KPC (NN / KC)      // 1536
#define NSTEP (KPC / 32)   // 48 K32-steps per chunk
#define MB 128             // rows per block (4 waves x 32 rows)
#define NMB (NN / MB)      // 96
#define NKSTEP (NN / 32)   // 384 total K32 steps

typedef __attribute__((ext_vector_type(8))) short short8;
typedef __attribute__((ext_vector_type(4))) float f32x4;

static __device__ __forceinline__ unsigned short f2bf_rn(float f) {
    unsigned int u = __float_as_uint(f);
    u += 0x7fffu + ((u >> 16) & 1u);   // round-to-nearest-even
    return (unsigned short)(u >> 16);
}

// ---------------- kernel 1: XW = x @ w (fp32, kept for epilogue) ----------------
// threads: NN*32; thread (i,c). Lanes sharing i broadcast x from L1; w coalesced.
__global__ __launch_bounds__(256) void build_xw(const float* __restrict__ x,
                                                const float* __restrict__ w,
                                                float* __restrict__ XW) {
    int t = blockIdx.x * blockDim.x + threadIdx.x;
    int i = t >> 5;
    int c = t & 31;
    if (i >= NN) return;
    float acc = 0.f;
#pragma unroll
    for (int k4 = 0; k4 < IN_CH / 4; ++k4) {
        float4 xv = *(const float4*)&x[(size_t)i * IN_CH + k4 * 4];
        acc = fmaf(xv.x, w[(k4 * 4 + 0) * OUT_CH + c], acc);
        acc = fmaf(xv.y, w[(k4 * 4 + 1) * OUT_CH + c], acc);
        acc = fmaf(xv.z, w[(k4 * 4 + 2) * OUT_CH + c], acc);
        acc = fmaf(xv.w, w[(k4 * 4 + 3) * OUT_CH + c], acc);
    }
    XW[(size_t)i * OUT_CH + c] = acc;
}

// ---------------- kernel 2: pack B into MFMA fragment order ----------------
// Bp[((s*8 + t)*64 + lane)*4 + d] : u32 = bf16 pair for k = s*32+(lane>>4)*8+2d (+1),
// col = t*16 + (lane&15). col<64 -> hi half, col>=64 -> lo half; (col&63)>=32 -> squared.
__global__ __launch_bounds__(256) void packb(const float* __restrict__ XW,
                                             unsigned int* __restrict__ Bp) {
    int idx = blockIdx.x * 256 + threadIdx.x;       // NKSTEP*512 threads
    int s = idx >> 9;
    int rem = idx & 511;
    int t = rem >> 6;
    int l = rem & 63;
    int kbase = s * 32 + ((l >> 4) * 8);
    int col = t * 16 + (l & 15);
    int cc = col & 31;
    bool sq = (col & 63) >= 32;
    bool lo = col >= 64;
    unsigned int out[4];
#pragma unroll
    for (int d = 0; d < 4; ++d) {
        unsigned short h[2];
#pragma unroll
        for (int j = 0; j < 2; ++j) {
            float v = XW[(size_t)(kbase + 2 * d + j) * OUT_CH + cc];
            if (sq) v *= v;
            unsigned short hb = f2bf_rn(v);
            if (lo) {
                float hf = __uint_as_float((unsigned int)hb << 16);
                hb = f2bf_rn(v - hf);
            }
            h[j] = hb;
        }
        out[d] = (unsigned int)h[0] | ((unsigned int)h[1] << 16);
    }
    *(uint4*)&Bp[(size_t)idx * 4] = *(uint4*)out;
}

// ---------------- kernel 3: streamed MFMA C = E @ B, rowsums ----------------
// grid = NMB*KC blocks; block = 4 waves x 32-row strips; E global->reg->bf16, no LDS.
__global__ __launch_bounds__(256) void spmm(const float* __restrict__ E,
                                            const unsigned int* __restrict__ Bp,
                                            float* __restrict__ S,
                                            float* __restrict__ RS) {
    const int mb = blockIdx.x % NMB;
    const int kc = blockIdx.x / NMB;
    const int tid = threadIdx.x;
    const int wid = tid >> 6;
    const int lane = tid & 63;
    const int r0 = mb * MB + wid * 32;          // wave's 32-row strip
    const int row0 = r0 + (lane & 15);          // mtile 0 row for this lane
    const int kq = (lane >> 4) * 8;             // k offset within the 32-step

    f32x4 acc[2][8] = {};
    float rs[2] = {0.f, 0.f};

    const float* e0p = E + (size_t)row0 * NN + kc * KPC + kq;
    const float* e1p = e0p + (size_t)16 * NN;

    for (int s = 0; s < NSTEP; ++s) {
        const int koff = s * 32;
        float4 a0 = *(const float4*)(e0p + koff);
        float4 a1 = *(const float4*)(e0p + koff + 4);
        float4 c0 = *(const float4*)(e1p + koff);
        float4 c1 = *(const float4*)(e1p + koff + 4);

        const unsigned int* bp = Bp + (size_t)(kc * NSTEP + s) * 2048 + lane * 4;
        uint4 b[8];
#pragma unroll
        for (int t = 0; t < 8; ++t)
            b[t] = *(const uint4*)(bp + t * 256);

        // pack E to bf16 (exact: values are 0.0/1.0, truncation lossless)
        union { unsigned int u[4]; short8 v; } pa, pb;
        pa.u[0] = (__float_as_uint(a0.x) >> 16) | (__float_as_uint(a0.y) & 0xffff0000u);
        pa.u[1] = (__float_as_uint(a0.z) >> 16) | (__float_as_uint(a0.w) & 0xffff0000u);
        pa.u[2] = (__float_as_uint(a1.x) >> 16) | (__float_as_uint(a1.y) & 0xffff0000u);
        pa.u[3] = (__float_as_uint(a1.z) >> 16) | (__float_as_uint(a1.w) & 0xffff0000u);
        pb.u[0] = (__float_as_uint(c0.x) >> 16) | (__float_as_uint(c0.y) & 0xffff0000u);
        pb.u[1] = (__float_as_uint(c0.z) >> 16) | (__float_as_uint(c0.w) & 0xffff0000u);
        pb.u[2] = (__float_as_uint(c1.x) >> 16) | (__float_as_uint(c1.y) & 0xffff0000u);
        pb.u[3] = (__float_as_uint(c1.z) >> 16) | (__float_as_uint(c1.w) & 0xffff0000u);

        rs[0] += ((a0.x + a0.y) + (a0.z + a0.w)) + ((a1.x + a1.y) + (a1.z + a1.w));
        rs[1] += ((c0.x + c0.y) + (c0.z + c0.w)) + ((c1.x + c1.y) + (c1.z + c1.w));

#pragma unroll
        for (int t = 0; t < 8; ++t) {
            union { uint4 q; short8 v; } bu;
            bu.q = b[t];
            acc[0][t] = __builtin_amdgcn_mfma_f32_16x16x32_bf16(pa.v, bu.v, acc[0][t], 0, 0, 0);
            acc[1][t] = __builtin_amdgcn_mfma_f32_16x16x32_bf16(pb.v, bu.v, acc[1][t], 0, 0, 0);
        }
    }

    // rowsum reduce: lanes {l, l+16, l+32, l+48} hold k-octet partials of one row
#pragma unroll
    for (int m = 0; m < 2; ++m) {
        float v = rs[m];
        v += __shfl_xor(v, 16, 64);
        v += __shfl_xor(v, 32, 64);
        if ((lane >> 4) == 0)
            atomicAdd(&RS[r0 + m * 16 + (lane & 15)], v);
    }

    // C/D layout (m89-verified): col = lane&15, row = (lane>>4)*4 + reg
    // merge hi (tile t) + lo (tile t+4) channel halves before the atomic
#pragma unroll
    for (int m = 0; m < 2; ++m) {
        const int rowb = r0 + m * 16 + (lane >> 4) * 4;
#pragma unroll
        for (int t = 0; t < 4; ++t) {
#pragma unroll
            for (int r = 0; r < 4; ++r) {
                float v = acc[m][t][r] + acc[m][t + 4][r];
                atomicAdd(&S[(size_t)(rowb + r) * 64 + t * 16 + (lane & 15)], v);
            }
        }
    }
}

// ---------------- kernel 4: epilogue ----------------
__global__ __launch_bounds__(256) void epi(const float* __restrict__ E,
                                           const float* __restrict__ XW,
                                           const float* __restrict__ S,
                                           const float* __restrict__ RS,
                                           const float* __restrict__ bias,
                                           float* __restrict__ out) {
    int t = blockIdx.x * blockDim.x + threadIdx.x;  // NN*32 threads
    int i = t >> 5;
    int c = t & 31;
    if (i >= NN) return;
    const float eii = E[(size_t)i * NN + i];            // 0 or 1
    const float xwc = XW[(size_t)i * OUT_CH + c];
    const float xw2c = xwc * xwc;
    const float s = S[(size_t)i * 64 + c] + xwc;
    const float tt = S[(size_t)i * 64 + 32 + c] + (eii != 0.f ? 3.f : 1.f) * xw2c;
    const float rse = RS[i];
    const float rsa = rse + 1.f;
    const float d1 = eii + 1.f;
    const float sumsq = rse - eii + d1 * d1;
    const float denom = rsa * rsa - sumsq;
    const float nrm = (denom == 0.f) ? 0.f : 1.f / denom;
    out[(size_t)i * OUT_CH + c] = nrm * (s * s - tt) + bias[c];
}

extern "C" void kernel_launch(void* const* d_in, const int* in_sizes, int n_in,
                              void* d_out, int out_size, void* d_ws, size_t ws_size,
                              hipStream_t stream) {
    const float* x    = (const float*)d_in[0];
    const float* E    = (const float*)d_in[1];
    const float* w    = (const float*)d_in[2];
    const float* bias = (const float*)d_in[3];
    float* out = (float*)d_out;

    // ws layout: XW [NN*32] f32 | Bp [NKSTEP*512*4] u32 | S [NN*64] f32 | RS [NN] f32  (~7.9 MB)
    float* XW = (float*)d_ws;
    unsigned int* Bp = (unsigned int*)(XW + (size_t)NN * OUT_CH);
    float* S = (float*)(Bp + (size_t)NKSTEP * 512 * 4);
    float* RS = S + (size_t)NN * 64;

    // zero accumulators (ws is re-poisoned 0xAA before every timed launch)
    hipMemsetAsync(S, 0, ((size_t)NN * 64 + NN) * sizeof(float), stream);

    build_xw<<<NN * OUT_CH / 256, 256, 0, stream>>>(x, w, XW);
    packb<<<NKSTEP * 512 / 256, 256, 0, stream>>>(XW, Bp);
    spmm<<<NMB * KC, 256, 0, stream>>>(E, Bp, S, RS);
    epi<<<NN * OUT_CH / 256, 256, 0, stream>>>(E, XW, S, RS, bias, out);
}